// Round 5
// baseline (213.459 us; speedup 1.0000x reference)
//
#include <hip/hip_runtime.h>
#include <math.h>

// Problem constants (fixed by the reference)
#define NSEG 32
#define T_DIM 8
#define F_DIM 32
#define P_DIM 8
#define TF 256           // T_DIM * F_DIM
#define OUT_PER_SEG 2048 // T*P*F
#define EPS_DENOM 1e-16f

#define CHUNK 64
#define K2_THREADS 256
#define NPG (CHUNK / 4)   // 4 waves per block, 16 nodes each

// Tiny MLP: h = elu(pos @ W1 + b1) @ W2 + b2  (per node, P=8 outputs)
__device__ __forceinline__ void compute_h(
    float h[P_DIM], const float* __restrict__ pos, int n,
    const float* __restrict__ W1, const float* __restrict__ b1,
    const float* __restrict__ W2, const float* __restrict__ b2) {
  float p0 = pos[3 * n + 0];
  float p1 = pos[3 * n + 1];
  float p2 = pos[3 * n + 2];
  float a[P_DIM];
#pragma unroll
  for (int p = 0; p < P_DIM; p++) {
    float v = b1[p] + p0 * W1[0 * P_DIM + p] + p1 * W1[1 * P_DIM + p] + p2 * W1[2 * P_DIM + p];
    a[p] = v > 0.f ? v : (__expf(v) - 1.f);  // ELU, alpha=1
  }
#pragma unroll
  for (int p = 0; p < P_DIM; p++) {
    float v = b2[p];
#pragma unroll
    for (int j = 0; j < P_DIM; j++) v += a[j] * W2[j * P_DIM + p];
    h[p] = v;
  }
}

// Kernel 0: zero the output (boundary-block atomics land in it before reduce).
__global__ __launch_bounds__(256) void zero_kernel(float* __restrict__ out, int nf) {
  int i = (blockIdx.x * 256 + threadIdx.x) * 8;
  if (i + 8 <= nf) {
    float4* o = reinterpret_cast<float4*>(out + i);
    float4 z = make_float4(0.f, 0.f, 0.f, 0.f);
    o[0] = z;
    o[1] = z;
  }
}

// per-node FMA: acc[p] (float4 over f) += e[p] * x[n, t, f..f+3]
#define FMA_NODE(ii, xv) do {                                                  \
    const float4* _wr = reinterpret_cast<const float4*>(&wbuf[(ii)][0]);       \
    float4 _wa = _wr[0], _wb = _wr[1];                                         \
    acc[0].x += _wa.x*(xv).x; acc[0].y += _wa.x*(xv).y;                        \
    acc[0].z += _wa.x*(xv).z; acc[0].w += _wa.x*(xv).w;                        \
    acc[1].x += _wa.y*(xv).x; acc[1].y += _wa.y*(xv).y;                        \
    acc[1].z += _wa.y*(xv).z; acc[1].w += _wa.y*(xv).w;                        \
    acc[2].x += _wa.z*(xv).x; acc[2].y += _wa.z*(xv).y;                        \
    acc[2].z += _wa.z*(xv).z; acc[2].w += _wa.z*(xv).w;                        \
    acc[3].x += _wa.w*(xv).x; acc[3].y += _wa.w*(xv).y;                        \
    acc[3].z += _wa.w*(xv).z; acc[3].w += _wa.w*(xv).w;                        \
    acc[4].x += _wb.x*(xv).x; acc[4].y += _wb.x*(xv).y;                        \
    acc[4].z += _wb.x*(xv).z; acc[4].w += _wb.x*(xv).w;                        \
    acc[5].x += _wb.y*(xv).x; acc[5].y += _wb.y*(xv).y;                        \
    acc[5].z += _wb.y*(xv).z; acc[5].w += _wb.y*(xv).w;                        \
    acc[6].x += _wb.z*(xv).x; acc[6].y += _wb.z*(xv).y;                        \
    acc[6].z += _wb.z*(xv).z; acc[6].w += _wb.z*(xv).w;                        \
    acc[7].x += _wb.w*(xv).x; acc[7].y += _wb.w*(xv).y;                        \
    acc[7].z += _wb.w*(xv).z; acc[7].w += _wb.w*(xv).w;                        \
  } while (0)

// flush accumulators via scalar f32 atomics (boundary blocks only)
__device__ __forceinline__ void flush_group(float* __restrict__ out, int sg, int c,
                                            float4 acc[P_DIM]) {
  float* o = out + (size_t)sg * OUT_PER_SEG + (c >> 3) * (P_DIM * F_DIM) + (c & 7) * 4;
#pragma unroll
  for (int p = 0; p < P_DIM; p++) {
    float* op = o + p * F_DIM;
    unsafeAtomicAdd(op + 0, acc[p].x);
    unsafeAtomicAdd(op + 1, acc[p].y);
    unsafeAtomicAdd(op + 2, acc[p].z);
    unsafeAtomicAdd(op + 3, acc[p].w);
    acc[p] = make_float4(0.f, 0.f, 0.f, 0.f);
  }
}

// Kernel 1: block = 64 consecutive nodes, UNNORMALIZED accumulation of
// exp(h[n,p]) * x[n,t,f] (denominator applied in reduce_kernel).
// Sized for 8 co-resident blocks/CU (32 waves/CU): LDS ~10.5 KB, VGPR <= 64
// via __launch_bounds__(256,8) -- maximizes loads-in-flight per CU, which is
// the binding constraint (accum is ~95% memory-latency stall at 12 waves/CU).
// Phase A: e-weights into LDS (wave 0). Phase B: 4 waves x 64 float4-columns,
// each wave streams 16 contiguous nodes, batch-8 loads (compiler-scheduled,
// r2-measured 56 VGPR body). Cross-wave reduce: turn-wise add into an 8 KB
// facc tile (4 barriers), then one plain float4-store partial slot per block.
__global__ __launch_bounds__(K2_THREADS, 8) void accum_kernel(
    const float* __restrict__ x, const float* __restrict__ pos,
    const int* __restrict__ seg,
    const float* __restrict__ W1, const float* __restrict__ b1,
    const float* __restrict__ W2, const float* __restrict__ b2,
    float* __restrict__ out, float* __restrict__ part,
    int* __restrict__ segtag, int N) {
  __shared__ __align__(16) float wbuf[CHUNK][P_DIM];   // 2 KB
  __shared__ int sbuf[CHUNK];                          // 256 B
  __shared__ float4 facc[P_DIM][64];                   // 8 KB

  int base = blockIdx.x * CHUNK;
  int cnt = N - base;
  if (cnt > CHUNK) cnt = CHUNK;
  int tid = threadIdx.x;

  // Phase A: e[node][p] = exp(h)
  if (tid < cnt) {
    int n = base + tid;
    sbuf[tid] = seg[n];
    float h[P_DIM];
    compute_h(h, pos, n, W1, b1, W2, b2);
#pragma unroll
    for (int p = 0; p < P_DIM; p++)
      wbuf[tid][p] = __expf(h[p]);
  }
  __syncthreads();

  int c = tid & 63;   // column: t = c>>3, f = (c&7)*4
  int g = tid >> 6;   // wave group, owns nodes [g*16, g*16+16)
  int i0 = g * NPG;
  int i1 = i0 + NPG;
  if (i1 > cnt) i1 = cnt;
  if (i0 > cnt) i0 = cnt;

  const float4* xp = reinterpret_cast<const float4*>(x) + (size_t)base * (TF / 4) + c;

  float4 acc[P_DIM];
#pragma unroll
  for (int p = 0; p < P_DIM; p++) acc[p] = make_float4(0.f, 0.f, 0.f, 0.f);

  bool single = (sbuf[0] == sbuf[cnt - 1]);  // block-uniform
  if (tid == 0) segtag[blockIdx.x] = single ? sbuf[0] : -1;

  if (single) {
    int i = i0;
    for (; i + 8 <= i1; i += 8) {
      float4 xv[8];
#pragma unroll
      for (int j = 0; j < 8; j++) xv[j] = xp[(size_t)(i + j) * (TF / 4)];
#pragma unroll
      for (int j = 0; j < 8; j++) FMA_NODE(i + j, xv[j]);
    }
    for (; i < i1; ++i) {
      float4 xv = xp[(size_t)i * (TF / 4)];
      FMA_NODE(i, xv);
    }

    // turn-wise cross-wave reduce into the shared 8 KB tile (uniform branches)
#pragma unroll
    for (int turn = 0; turn < 4; ++turn) {
      if (g == turn) {
        if (turn == 0) {
#pragma unroll
          for (int p = 0; p < P_DIM; p++) facc[p][c] = acc[p];
        } else {
#pragma unroll
          for (int p = 0; p < P_DIM; p++) {
            float4 v = facc[p][c];
            v.x += acc[p].x; v.y += acc[p].y; v.z += acc[p].z; v.w += acc[p].w;
            facc[p][c] = v;
          }
        }
      }
      __syncthreads();
    }

    // all 256 threads: each stores 8 consecutive floats of the partial slot
    int t = tid >> 5;
    int p = (tid >> 2) & 7;
    int fb = tid & 3;
    int c0 = t * 8 + fb * 2;
    float4 A = facc[p][c0];
    float4 B = facc[p][c0 + 1];
    int off = t * (P_DIM * F_DIM) + p * F_DIM + fb * 8;
    float4* po = reinterpret_cast<float4*>(
        part + (size_t)blockIdx.x * OUT_PER_SEG + off);
    po[0] = A;
    po[1] = B;
  } else {
    // Boundary block (~31 of 1563): stream run-by-run, flush each run via
    // atomics into out (unnormalized; reduce_kernel scales later).
    int i = i0;
    while (i < i1) {
      int cur = sbuf[i];
      int j = i + 1;
      while (j < i1 && sbuf[j] == cur) j++;
      int k = i;
      for (; k + 4 <= j; k += 4) {
        float4 xv0 = xp[(size_t)(k + 0) * (TF / 4)];
        float4 xv1 = xp[(size_t)(k + 1) * (TF / 4)];
        float4 xv2 = xp[(size_t)(k + 2) * (TF / 4)];
        float4 xv3 = xp[(size_t)(k + 3) * (TF / 4)];
        FMA_NODE(k + 0, xv0);
        FMA_NODE(k + 1, xv1);
        FMA_NODE(k + 2, xv2);
        FMA_NODE(k + 3, xv3);
      }
      for (; k < j; ++k) {
        float4 xv = xp[(size_t)k * (TF / 4)];
        FMA_NODE(k, xv);
      }
      flush_group(out, cur, c, acc);
      i = j;
    }
  }
}

// Kernel 2: one block per segment. Computes the softmax denominator (sum of
// exp(h) over the segment's nodes), then
//   out = (out_atomic + sum of tagged partial slots) * inv_den.
__global__ __launch_bounds__(256) void reduce_kernel(
    const int* __restrict__ seg, const int* __restrict__ segtag,
    const float* __restrict__ part, const float* __restrict__ pos,
    const float* __restrict__ W1, const float* __restrict__ b1,
    const float* __restrict__ W2, const float* __restrict__ b2,
    float* __restrict__ out, int N) {
  int s = blockIdx.x;
  int tid = threadIdx.x;

  // bounds of segment s (uniform across threads)
  int lo = 0, hi = N;
  while (lo < hi) { int mid = (lo + hi) >> 1; if (seg[mid] < s) lo = mid + 1; else hi = mid; }
  int start = lo;
  lo = start; hi = N;
  while (lo < hi) { int mid = (lo + hi) >> 1; if (seg[mid] < s + 1) lo = mid + 1; else hi = mid; }
  int end = lo;
  if (start >= end) return;  // empty segment: out stays zero

  // denominator: sum of exp(h) over the segment's nodes
  float lsum[P_DIM];
#pragma unroll
  for (int p = 0; p < P_DIM; p++) lsum[p] = 0.f;
  for (int i = start + tid; i < end; i += 256) {
    float h[P_DIM];
    compute_h(h, pos, i, W1, b1, W2, b2);
#pragma unroll
    for (int p = 0; p < P_DIM; p++) lsum[p] += __expf(h[p]);
  }
#pragma unroll
  for (int off = 32; off >= 1; off >>= 1)
#pragma unroll
    for (int p = 0; p < P_DIM; p++)
      lsum[p] += __shfl_down(lsum[p], off, 64);

  __shared__ float wred[P_DIM][4];
  __shared__ float invd[P_DIM];
  int wid = tid >> 6, lane = tid & 63;
  if (lane == 0) {
#pragma unroll
    for (int p = 0; p < P_DIM; p++) wred[p][wid] = lsum[p];
  }
  __syncthreads();
  if (tid < P_DIM) {
    float ss = wred[tid][0] + wred[tid][1] + wred[tid][2] + wred[tid][3];
    invd[tid] = 1.f / (ss + EPS_DENOM);
  }
  __syncthreads();

  // combine tagged partials + boundary atomic contributions, scale, store
  int b0 = start / CHUNK;
  int b1i = (end - 1) / CHUNK;
  int p = (tid >> 2) & 7;  // out layout: [t][p][f], tid*8 = t*256 + p*32 + fb*8
  float s0 = invd[p];

  float* o = out + (size_t)s * OUT_PER_SEG + tid * 8;
  float4 A = reinterpret_cast<float4*>(o)[0];
  float4 B = reinterpret_cast<float4*>(o)[1];
  for (int b = b0; b <= b1i; b++) {
    if (segtag[b] == s) {
      const float4* pp = reinterpret_cast<const float4*>(
          part + (size_t)b * OUT_PER_SEG + tid * 8);
      float4 a2 = pp[0], b2v = pp[1];
      A.x += a2.x;  A.y += a2.y;  A.z += a2.z;  A.w += a2.w;
      B.x += b2v.x; B.y += b2v.y; B.z += b2v.z; B.w += b2v.w;
    }
  }
  A.x *= s0; A.y *= s0; A.z *= s0; A.w *= s0;
  B.x *= s0; B.y *= s0; B.z *= s0; B.w *= s0;
  reinterpret_cast<float4*>(o)[0] = A;
  reinterpret_cast<float4*>(o)[1] = B;
}

extern "C" void kernel_launch(void* const* d_in, const int* in_sizes, int n_in,
                              void* d_out, int out_size, void* d_ws, size_t ws_size,
                              hipStream_t stream) {
  const float* pos = (const float*)d_in[0];
  const float* x   = (const float*)d_in[1];
  const int*   seg = (const int*)d_in[2];
  const float* W1  = (const float*)d_in[3];
  const float* b1  = (const float*)d_in[4];
  const float* W2  = (const float*)d_in[5];
  const float* b2  = (const float*)d_in[6];
  float* out = (float*)d_out;
  int N = in_sizes[2];
  int nblk = (N + CHUNK - 1) / CHUNK;

  // workspace layout: segtag [nblk i32] | partials [nblk*2048 f32]
  char* ws = (char*)d_ws;
  size_t part_off = ((size_t)nblk * 4 + 255) & ~(size_t)255;
  int* segtag = (int*)ws;
  float* part = (float*)(ws + part_off);

  int zblk = (out_size / 8 + 255) / 256;
  zero_kernel<<<zblk, 256, 0, stream>>>(out, out_size);

  accum_kernel<<<nblk, K2_THREADS, 0, stream>>>(
      x, pos, seg, W1, b1, W2, b2, out, part, segtag, N);

  reduce_kernel<<<NSEG, 256, 0, stream>>>(
      seg, segtag, part, pos, W1, b1, W2, b2, out, N);
}

// Round 6
// 210.927 us; speedup vs baseline: 1.0120x; 1.0120x over previous
//
#include <hip/hip_runtime.h>
#include <math.h>

// Problem constants (fixed by the reference)
#define NSEG 32
#define T_DIM 8
#define F_DIM 32
#define P_DIM 8
#define TF 256           // T_DIM * F_DIM
#define OUT_PER_SEG 2048 // T*P*F
#define EPS_DENOM 1e-16f

#define CHUNK 256
#define K2_THREADS 256
#define NPW 64            // nodes per wave (4 waves/block)
#define SLOTS_PER_WAVE 2
#define SLOTS_PER_BLOCK 8 // 4 waves * 2

// Tiny MLP: h = elu(pos @ W1 + b1) @ W2 + b2  (per node, P=8 outputs)
__device__ __forceinline__ void compute_h(
    float h[P_DIM], const float* __restrict__ pos, int n,
    const float* __restrict__ W1, const float* __restrict__ b1,
    const float* __restrict__ W2, const float* __restrict__ b2) {
  float p0 = pos[3 * n + 0];
  float p1 = pos[3 * n + 1];
  float p2 = pos[3 * n + 2];
  float a[P_DIM];
#pragma unroll
  for (int p = 0; p < P_DIM; p++) {
    float v = b1[p] + p0 * W1[0 * P_DIM + p] + p1 * W1[1 * P_DIM + p] + p2 * W1[2 * P_DIM + p];
    a[p] = v > 0.f ? v : (__expf(v) - 1.f);  // ELU, alpha=1
  }
#pragma unroll
  for (int p = 0; p < P_DIM; p++) {
    float v = b2[p];
#pragma unroll
    for (int j = 0; j < P_DIM; j++) v += a[j] * W2[j * P_DIM + p];
    h[p] = v;
  }
}

// Kernel 0: zero the output (only the never-in-practice 3rd-run-within-a-wave
// atomics land in it before reduce_kernel reads it). ~1 MB, ~1 us.
__global__ __launch_bounds__(256) void zero_kernel(float* __restrict__ out, int nf) {
  int i = (blockIdx.x * 256 + threadIdx.x) * 8;
  if (i + 8 <= nf) {
    float4* o = reinterpret_cast<float4*>(out + i);
    float4 z = make_float4(0.f, 0.f, 0.f, 0.f);
    o[0] = z;
    o[1] = z;
  }
}

// per-node FMA: acc[p] (float4 over f) += e[p] * x[n, t, f..f+3]
#define FMA_NODE(ii, xv) do {                                                  \
    const float4* _wr = reinterpret_cast<const float4*>(&wbuf[(ii)][0]);       \
    float4 _wa = _wr[0], _wb = _wr[1];                                         \
    acc[0].x += _wa.x*(xv).x; acc[0].y += _wa.x*(xv).y;                        \
    acc[0].z += _wa.x*(xv).z; acc[0].w += _wa.x*(xv).w;                        \
    acc[1].x += _wa.y*(xv).x; acc[1].y += _wa.y*(xv).y;                        \
    acc[1].z += _wa.y*(xv).z; acc[1].w += _wa.y*(xv).w;                        \
    acc[2].x += _wa.z*(xv).x; acc[2].y += _wa.z*(xv).y;                        \
    acc[2].z += _wa.z*(xv).z; acc[2].w += _wa.z*(xv).w;                        \
    acc[3].x += _wa.w*(xv).x; acc[3].y += _wa.w*(xv).y;                        \
    acc[3].z += _wa.w*(xv).z; acc[3].w += _wa.w*(xv).w;                        \
    acc[4].x += _wb.x*(xv).x; acc[4].y += _wb.x*(xv).y;                        \
    acc[4].z += _wb.x*(xv).z; acc[4].w += _wb.x*(xv).w;                        \
    acc[5].x += _wb.y*(xv).x; acc[5].y += _wb.y*(xv).y;                        \
    acc[5].z += _wb.y*(xv).z; acc[5].w += _wb.y*(xv).w;                        \
    acc[6].x += _wb.z*(xv).x; acc[6].y += _wb.z*(xv).y;                        \
    acc[6].z += _wb.z*(xv).z; acc[6].w += _wb.z*(xv).w;                        \
    acc[7].x += _wb.w*(xv).x; acc[7].y += _wb.w*(xv).y;                        \
    acc[7].z += _wb.w*(xv).z; acc[7].w += _wb.w*(xv).w;                        \
  } while (0)

// plain coalesced store of one wave's accumulators into its private slot:
// part4[slot*512 + p*64 + c]  (for fixed p: 64 lanes x 16B = 1KB contiguous)
__device__ __forceinline__ void store_slot(float* __restrict__ part, int slot,
                                           int c, float4 acc[P_DIM]) {
  float4* po = reinterpret_cast<float4*>(part) + (size_t)slot * 512 + c;
#pragma unroll
  for (int p = 0; p < P_DIM; p++) po[p * 64] = acc[p];
}

// atomic fallback (segment shorter than a wave's run budget; ~never)
__device__ __forceinline__ void flush_atomic(float* __restrict__ out, int sg, int c,
                                             float4 acc[P_DIM]) {
  float* o = out + (size_t)sg * OUT_PER_SEG + (c >> 3) * (P_DIM * F_DIM) + (c & 7) * 4;
#pragma unroll
  for (int p = 0; p < P_DIM; p++) {
    float* op = o + p * F_DIM;
    unsafeAtomicAdd(op + 0, acc[p].x);
    unsafeAtomicAdd(op + 1, acc[p].y);
    unsafeAtomicAdd(op + 2, acc[p].z);
    unsafeAtomicAdd(op + 3, acc[p].w);
  }
}

// Kernel 1: block = 256 consecutive nodes, UNNORMALIZED accumulation of
// exp(h[n,p]) * x[n,t,f] (denominator applied in reduce_kernel).
// Phase A: e-weights into LDS (all 256 threads). Phase B: each of the 4 waves
// independently streams its own 64 nodes (batch-8 float4 loads) and writes its
// partial tile(s) with PLAIN stores to private slots -- zero atomics on every
// practical path, no cross-wave reduce, no post-phase-A barriers.
// Runs are processed sequentially with a single acc set (no r4 register bloat).
// Every slot tag is written every iteration (workspace is poisoned).
__global__ __launch_bounds__(K2_THREADS) void accum_kernel(
    const float* __restrict__ x, const float* __restrict__ pos,
    const int* __restrict__ seg,
    const float* __restrict__ W1, const float* __restrict__ b1,
    const float* __restrict__ W2, const float* __restrict__ b2,
    float* __restrict__ out, float* __restrict__ part,
    int* __restrict__ segtag, int N) {
  __shared__ __align__(16) float wbuf[CHUNK][P_DIM];   // 8 KB
  __shared__ int sbuf[CHUNK];                          // 1 KB

  int base = blockIdx.x * CHUNK;
  int cnt = N - base;
  if (cnt > CHUNK) cnt = CHUNK;
  int tid = threadIdx.x;

  // Phase A: e[node][p] = exp(h)
  if (tid < cnt) {
    int n = base + tid;
    sbuf[tid] = seg[n];
    float h[P_DIM];
    compute_h(h, pos, n, W1, b1, W2, b2);
#pragma unroll
    for (int p = 0; p < P_DIM; p++)
      wbuf[tid][p] = __expf(h[p]);
  }
  __syncthreads();

  int c = tid & 63;   // column: t = c>>3, f = (c&7)*4
  int g = tid >> 6;   // wave id; owns nodes [g*64, g*64+64)
  int i0 = g * NPW;
  int i1 = i0 + NPW;
  if (i1 > cnt) i1 = cnt;

  const float4* xp = reinterpret_cast<const float4*>(x) + (size_t)base * (TF / 4) + c;

  float4 acc[P_DIM];
#pragma unroll
  for (int p = 0; p < P_DIM; p++) acc[p] = make_float4(0.f, 0.f, 0.f, 0.f);

  int sb = blockIdx.x * SLOTS_PER_BLOCK + g * SLOTS_PER_WAVE;
  int nrun = 0;  // stored runs (max 2)

  if (i0 < i1) {
    if (sbuf[i0] == sbuf[i1 - 1]) {
      // uniform wave (99.5% case): batch-8 pipelined stream of 64 nodes
      int i = i0;
      for (; i + 8 <= i1; i += 8) {
        float4 xv[8];
#pragma unroll
        for (int j = 0; j < 8; j++) xv[j] = xp[(size_t)(i + j) * (TF / 4)];
#pragma unroll
        for (int j = 0; j < 8; j++) FMA_NODE(i + j, xv[j]);
      }
      for (; i < i1; ++i) {
        float4 xv = xp[(size_t)i * (TF / 4)];
        FMA_NODE(i, xv);
      }
      store_slot(part, sb, c, acc);
      if (c == 0) segtag[sb] = sbuf[i0];
      nrun = 1;
    } else {
      // boundary wave: process runs sequentially, single acc set
      int i = i0;
      while (i < i1) {
        int cur = sbuf[i];
        int j = i + 1;
        while (j < i1 && sbuf[j] == cur) j++;
        int k = i;
        for (; k + 4 <= j; k += 4) {
          float4 xv0 = xp[(size_t)(k + 0) * (TF / 4)];
          float4 xv1 = xp[(size_t)(k + 1) * (TF / 4)];
          float4 xv2 = xp[(size_t)(k + 2) * (TF / 4)];
          float4 xv3 = xp[(size_t)(k + 3) * (TF / 4)];
          FMA_NODE(k + 0, xv0);
          FMA_NODE(k + 1, xv1);
          FMA_NODE(k + 2, xv2);
          FMA_NODE(k + 3, xv3);
        }
        for (; k < j; ++k) {
          float4 xv = xp[(size_t)k * (TF / 4)];
          FMA_NODE(k, xv);
        }
        if (nrun < SLOTS_PER_WAVE) {
          store_slot(part, sb + nrun, c, acc);
          if (c == 0) segtag[sb + nrun] = cur;
          nrun++;
        } else {
          flush_atomic(out, cur, c, acc);  // segment < 63 nodes; ~never
        }
#pragma unroll
        for (int p = 0; p < P_DIM; p++) acc[p] = make_float4(0.f, 0.f, 0.f, 0.f);
        i = j;
      }
    }
  }
  // tag unused slots invalid (segtag is poisoned between iterations!)
  if (c == 0) {
    for (int r = nrun; r < SLOTS_PER_WAVE; r++) segtag[sb + r] = -1;
  }
}

// Kernel 2: one block per segment. Computes the softmax denominator (sum of
// exp(h) over the segment's nodes), then
//   out = (out_atomic + sum of tagged wave slots) * inv_den.
// Slot layout: float4[slot][p][c] with c = t*8 + f/4.
__global__ __launch_bounds__(256) void reduce_kernel(
    const int* __restrict__ seg, const int* __restrict__ segtag,
    const float* __restrict__ part, const float* __restrict__ pos,
    const float* __restrict__ W1, const float* __restrict__ b1,
    const float* __restrict__ W2, const float* __restrict__ b2,
    float* __restrict__ out, int N) {
  int s = blockIdx.x;
  int tid = threadIdx.x;

  // bounds of segment s (uniform across threads)
  int lo = 0, hi = N;
  while (lo < hi) { int mid = (lo + hi) >> 1; if (seg[mid] < s) lo = mid + 1; else hi = mid; }
  int start = lo;
  lo = start; hi = N;
  while (lo < hi) { int mid = (lo + hi) >> 1; if (seg[mid] < s + 1) lo = mid + 1; else hi = mid; }
  int end = lo;
  if (start >= end) return;  // empty segment: out stays zero

  // denominator: sum of exp(h) over the segment's nodes
  float lsum[P_DIM];
#pragma unroll
  for (int p = 0; p < P_DIM; p++) lsum[p] = 0.f;
  for (int i = start + tid; i < end; i += 256) {
    float h[P_DIM];
    compute_h(h, pos, i, W1, b1, W2, b2);
#pragma unroll
    for (int p = 0; p < P_DIM; p++) lsum[p] += __expf(h[p]);
  }
#pragma unroll
  for (int off = 32; off >= 1; off >>= 1)
#pragma unroll
    for (int p = 0; p < P_DIM; p++)
      lsum[p] += __shfl_down(lsum[p], off, 64);

  __shared__ float wred[P_DIM][4];
  __shared__ float invd[P_DIM];
  int wid = tid >> 6, lane = tid & 63;
  if (lane == 0) {
#pragma unroll
    for (int p = 0; p < P_DIM; p++) wred[p][wid] = lsum[p];
  }
  __syncthreads();
  if (tid < P_DIM) {
    float ss = wred[tid][0] + wred[tid][1] + wred[tid][2] + wred[tid][3];
    invd[tid] = 1.f / (ss + EPS_DENOM);
  }
  __syncthreads();

  // combine tagged wave slots + (rare) atomic contributions, scale, store
  int b0 = start / CHUNK;
  int b1i = (end - 1) / CHUNK;
  int t = tid >> 5;
  int p = (tid >> 2) & 7;  // out layout: [t][p][f], tid*8 = t*256 + p*32 + fb*8
  int fb = tid & 3;
  float s0 = invd[p];

  const float4* p4 = reinterpret_cast<const float4*>(part);
  int ridx = p * 64 + t * 8 + fb * 2;  // float4 index within a slot

  float* o = out + (size_t)s * OUT_PER_SEG + tid * 8;
  float4 A = reinterpret_cast<float4*>(o)[0];
  float4 B = reinterpret_cast<float4*>(o)[1];
  int slot_lo = b0 * SLOTS_PER_BLOCK;
  int slot_hi = b1i * SLOTS_PER_BLOCK + SLOTS_PER_BLOCK - 1;
  for (int sl = slot_lo; sl <= slot_hi; sl++) {
    if (segtag[sl] == s) {
      const float4* pp = p4 + (size_t)sl * 512 + ridx;
      float4 a2 = pp[0], b2v = pp[1];
      A.x += a2.x;  A.y += a2.y;  A.z += a2.z;  A.w += a2.w;
      B.x += b2v.x; B.y += b2v.y; B.z += b2v.z; B.w += b2v.w;
    }
  }
  A.x *= s0; A.y *= s0; A.z *= s0; A.w *= s0;
  B.x *= s0; B.y *= s0; B.z *= s0; B.w *= s0;
  reinterpret_cast<float4*>(o)[0] = A;
  reinterpret_cast<float4*>(o)[1] = B;
}

extern "C" void kernel_launch(void* const* d_in, const int* in_sizes, int n_in,
                              void* d_out, int out_size, void* d_ws, size_t ws_size,
                              hipStream_t stream) {
  const float* pos = (const float*)d_in[0];
  const float* x   = (const float*)d_in[1];
  const int*   seg = (const int*)d_in[2];
  const float* W1  = (const float*)d_in[3];
  const float* b1  = (const float*)d_in[4];
  const float* W2  = (const float*)d_in[5];
  const float* b2  = (const float*)d_in[6];
  float* out = (float*)d_out;
  int N = in_sizes[2];
  int nblk = (N + CHUNK - 1) / CHUNK;
  int nslots = nblk * SLOTS_PER_BLOCK;

  // workspace layout: segtag [nslots i32] | partials [nslots*2048 f32]
  char* ws = (char*)d_ws;
  size_t part_off = ((size_t)nslots * 4 + 255) & ~(size_t)255;
  int* segtag = (int*)ws;
  float* part = (float*)(ws + part_off);

  int zblk = (out_size / 8 + 255) / 256;
  zero_kernel<<<zblk, 256, 0, stream>>>(out, out_size);

  accum_kernel<<<nblk, K2_THREADS, 0, stream>>>(
      x, pos, seg, W1, b1, W2, b2, out, part, segtag, N);

  reduce_kernel<<<NSEG, 256, 0, stream>>>(
      seg, segtag, part, pos, W1, b1, W2, b2, out, N);
}

// Round 7
// 193.408 us; speedup vs baseline: 1.1037x; 1.0906x over previous
//
#include <hip/hip_runtime.h>
#include <math.h>

// Problem constants (fixed by the reference)
#define NSEG 32
#define T_DIM 8
#define F_DIM 32
#define P_DIM 8
#define TF 256           // T_DIM * F_DIM
#define OUT_PER_SEG 2048 // T*P*F
#define EPS_DENOM 1e-16f

#define CHUNK 256
#define K2_THREADS 256
#define NPW (CHUNK / 4)   // 4 waves per block, 64 nodes each

// Tiny MLP: h = elu(pos @ W1 + b1) @ W2 + b2  (per node, P=8 outputs)
__device__ __forceinline__ void compute_h(
    float h[P_DIM], const float* __restrict__ pos, int n,
    const float* __restrict__ W1, const float* __restrict__ b1,
    const float* __restrict__ W2, const float* __restrict__ b2) {
  float p0 = pos[3 * n + 0];
  float p1 = pos[3 * n + 1];
  float p2 = pos[3 * n + 2];
  float a[P_DIM];
#pragma unroll
  for (int p = 0; p < P_DIM; p++) {
    float v = b1[p] + p0 * W1[0 * P_DIM + p] + p1 * W1[1 * P_DIM + p] + p2 * W1[2 * P_DIM + p];
    a[p] = v > 0.f ? v : (__expf(v) - 1.f);  // ELU, alpha=1
  }
#pragma unroll
  for (int p = 0; p < P_DIM; p++) {
    float v = b2[p];
#pragma unroll
    for (int j = 0; j < P_DIM; j++) v += a[j] * W2[j * P_DIM + p];
    h[p] = v;
  }
}

// Kernel 0: zero the output (boundary-block atomics land in it before reduce).
__global__ __launch_bounds__(256) void zero_kernel(float* __restrict__ out, int nf) {
  int i = (blockIdx.x * 256 + threadIdx.x) * 8;
  if (i + 8 <= nf) {
    float4* o = reinterpret_cast<float4*>(out + i);
    float4 z = make_float4(0.f, 0.f, 0.f, 0.f);
    o[0] = z;
    o[1] = z;
  }
}

// per-node FMA: acc[p] (float4 over f) += e[p] * x[n, t, f..f+3]
#define FMA_NODE(ii, xv) do {                                                  \
    const float4* _wr = reinterpret_cast<const float4*>(&wbuf[(ii)][0]);       \
    float4 _wa = _wr[0], _wb = _wr[1];                                         \
    acc[0].x += _wa.x*(xv).x; acc[0].y += _wa.x*(xv).y;                        \
    acc[0].z += _wa.x*(xv).z; acc[0].w += _wa.x*(xv).w;                        \
    acc[1].x += _wa.y*(xv).x; acc[1].y += _wa.y*(xv).y;                        \
    acc[1].z += _wa.y*(xv).z; acc[1].w += _wa.y*(xv).w;                        \
    acc[2].x += _wa.z*(xv).x; acc[2].y += _wa.z*(xv).y;                        \
    acc[2].z += _wa.z*(xv).z; acc[2].w += _wa.z*(xv).w;                        \
    acc[3].x += _wa.w*(xv).x; acc[3].y += _wa.w*(xv).y;                        \
    acc[3].z += _wa.w*(xv).z; acc[3].w += _wa.w*(xv).w;                        \
    acc[4].x += _wb.x*(xv).x; acc[4].y += _wb.x*(xv).y;                        \
    acc[4].z += _wb.x*(xv).z; acc[4].w += _wb.x*(xv).w;                        \
    acc[5].x += _wb.y*(xv).x; acc[5].y += _wb.y*(xv).y;                        \
    acc[5].z += _wb.y*(xv).z; acc[5].w += _wb.y*(xv).w;                        \
    acc[6].x += _wb.z*(xv).x; acc[6].y += _wb.z*(xv).y;                        \
    acc[6].z += _wb.z*(xv).z; acc[6].w += _wb.z*(xv).w;                        \
    acc[7].x += _wb.w*(xv).x; acc[7].y += _wb.w*(xv).y;                        \
    acc[7].z += _wb.w*(xv).z; acc[7].w += _wb.w*(xv).w;                        \
  } while (0)

#define LOAD8(dst, i) do {                                                     \
    _Pragma("unroll")                                                          \
    for (int _j = 0; _j < 8; _j++) dst[_j] = xp[(size_t)((i) + _j) * (TF / 4)];\
  } while (0)

#define FMA8(src, i) do {                                                      \
    _Pragma("unroll")                                                          \
    for (int _j = 0; _j < 8; _j++) FMA_NODE((i) + _j, src[_j]);                \
  } while (0)

// flush accumulators via scalar f32 atomics (boundary blocks only; ~15 of 391)
__device__ __forceinline__ void flush_group(float* __restrict__ out, int sg, int c,
                                            float4 acc[P_DIM]) {
  float* o = out + (size_t)sg * OUT_PER_SEG + (c >> 3) * (P_DIM * F_DIM) + (c & 7) * 4;
#pragma unroll
  for (int p = 0; p < P_DIM; p++) {
    float* op = o + p * F_DIM;
    unsafeAtomicAdd(op + 0, acc[p].x);
    unsafeAtomicAdd(op + 1, acc[p].y);
    unsafeAtomicAdd(op + 2, acc[p].z);
    unsafeAtomicAdd(op + 3, acc[p].w);
    acc[p] = make_float4(0.f, 0.f, 0.f, 0.f);
  }
}

// Kernel 1: block = 256 consecutive nodes, UNNORMALIZED accumulation of
// exp(h[n,p]) * x[n,t,f] (denominator applied in reduce_kernel).
// Identical structure to the measured-best r3 kernel; the ONE change is the
// uniform-wave inner loop: an explicit 8+8 double-buffered rolling pipeline
// (8 float4 loads always in flight per wave), with __launch_bounds__(256,4)
// capping VGPR at 128 (~64 buf + 32 acc + addr fits; 4 waves/SIMD).
// Previous builds allocated only 56 VGPR -> ~2-deep load chain -> each wave
// was HBM-latency serialized (the invariant ~55us accum across r2-r6).
__global__ __launch_bounds__(K2_THREADS, 4) void accum_kernel(
    const float* __restrict__ x, const float* __restrict__ pos,
    const int* __restrict__ seg,
    const float* __restrict__ W1, const float* __restrict__ b1,
    const float* __restrict__ W2, const float* __restrict__ b2,
    float* __restrict__ out, float* __restrict__ part,
    int* __restrict__ segtag, int N) {
  __shared__ __align__(16) float wbuf[CHUNK][P_DIM];   // 8 KB
  __shared__ int sbuf[CHUNK];                          // 1 KB
  __shared__ float4 facc[P_DIM][4][64];                // 32 KB, [p][group][col]

  int base = blockIdx.x * CHUNK;
  int cnt = N - base;
  if (cnt > CHUNK) cnt = CHUNK;
  int tid = threadIdx.x;

  // Phase A: e[node][p] = exp(h)
  if (tid < cnt) {
    int n = base + tid;
    sbuf[tid] = seg[n];
    float h[P_DIM];
    compute_h(h, pos, n, W1, b1, W2, b2);
#pragma unroll
    for (int p = 0; p < P_DIM; p++)
      wbuf[tid][p] = __expf(h[p]);
  }
  __syncthreads();

  int c = tid & 63;   // column: t = c>>3, f = (c&7)*4
  int g = tid >> 6;   // wave group, owns nodes [g*64, g*64+64)
  int i0 = g * NPW;
  int i1 = i0 + NPW;
  if (i1 > cnt) i1 = cnt;
  if (i0 > cnt) i0 = cnt;

  const float4* xp = reinterpret_cast<const float4*>(x) + (size_t)base * (TF / 4) + c;

  float4 acc[P_DIM];
#pragma unroll
  for (int p = 0; p < P_DIM; p++) acc[p] = make_float4(0.f, 0.f, 0.f, 0.f);

  bool single = (sbuf[0] == sbuf[cnt - 1]);  // block-uniform
  if (tid == 0) segtag[blockIdx.x] = single ? sbuf[0] : -1;

  if (single) {
    if (i1 - i0 == NPW) {
      // full 64-node wave: 8+8 rolling double-buffer, 8 loads always in flight
      float4 xa[8], xb[8];
      LOAD8(xa, i0);
#pragma unroll
      for (int it = 0; it < 3; ++it) {
        int ib = i0 + it * 16;
        LOAD8(xb, ib + 8);
        FMA8(xa, ib);
        LOAD8(xa, ib + 16);
        FMA8(xb, ib + 8);
      }
      LOAD8(xb, i0 + 56);
      FMA8(xa, i0 + 48);
      FMA8(xb, i0 + 56);
    } else {
      // tail wave of the last block
      int i = i0;
      for (; i + 8 <= i1; i += 8) {
        float4 xv[8];
#pragma unroll
        for (int j = 0; j < 8; j++) xv[j] = xp[(size_t)(i + j) * (TF / 4)];
#pragma unroll
        for (int j = 0; j < 8; j++) FMA_NODE(i + j, xv[j]);
      }
      for (; i < i1; ++i) {
        float4 xv = xp[(size_t)i * (TF / 4)];
        FMA_NODE(i, xv);
      }
    }

    // stash per-group accumulators (contiguous 1KB per wave write)
#pragma unroll
    for (int p = 0; p < P_DIM; p++) facc[p][g][c] = acc[p];
    __syncthreads();

    // all 256 threads: reduce the 4 groups; each thread owns 8 consecutive floats
    int t = tid >> 5;
    int p = (tid >> 2) & 7;
    int fb = tid & 3;
    int c0 = t * 8 + fb * 2;
    float4 A = facc[p][0][c0];
    float4 B = facc[p][0][c0 + 1];
#pragma unroll
    for (int gg = 1; gg < 4; gg++) {
      float4 a2 = facc[p][gg][c0];
      float4 b2v = facc[p][gg][c0 + 1];
      A.x += a2.x;  A.y += a2.y;  A.z += a2.z;  A.w += a2.w;
      B.x += b2v.x; B.y += b2v.y; B.z += b2v.z; B.w += b2v.w;
    }
    int off = t * (P_DIM * F_DIM) + p * F_DIM + fb * 8;
    float4* po = reinterpret_cast<float4*>(part + (size_t)blockIdx.x * OUT_PER_SEG + off);
    po[0] = A;
    po[1] = B;
  } else {
    // Slow path: chunk spans segment boundaries (~15 of 391 blocks).
    // Stream run-by-run, flush each run via atomics into out (unnormalized).
    int i = i0;
    while (i < i1) {
      int cur = sbuf[i];
      int j = i + 1;
      while (j < i1 && sbuf[j] == cur) j++;
      int k = i;
      for (; k + 4 <= j; k += 4) {
        float4 xv0 = xp[(size_t)(k + 0) * (TF / 4)];
        float4 xv1 = xp[(size_t)(k + 1) * (TF / 4)];
        float4 xv2 = xp[(size_t)(k + 2) * (TF / 4)];
        float4 xv3 = xp[(size_t)(k + 3) * (TF / 4)];
        FMA_NODE(k + 0, xv0);
        FMA_NODE(k + 1, xv1);
        FMA_NODE(k + 2, xv2);
        FMA_NODE(k + 3, xv3);
      }
      for (; k < j; ++k) {
        float4 xv = xp[(size_t)k * (TF / 4)];
        FMA_NODE(k, xv);
      }
      flush_group(out, cur, c, acc);
      i = j;
    }
  }
}

// Kernel 2: one block per segment. Computes the softmax denominator (sum of
// exp(h) over the segment's nodes), then
//   out = (out_atomic + sum of tagged partial slots) * inv_den.
__global__ __launch_bounds__(256) void reduce_kernel(
    const int* __restrict__ seg, const int* __restrict__ segtag,
    const float* __restrict__ part, const float* __restrict__ pos,
    const float* __restrict__ W1, const float* __restrict__ b1,
    const float* __restrict__ W2, const float* __restrict__ b2,
    float* __restrict__ out, int N) {
  int s = blockIdx.x;
  int tid = threadIdx.x;

  // bounds of segment s (uniform across threads)
  int lo = 0, hi = N;
  while (lo < hi) { int mid = (lo + hi) >> 1; if (seg[mid] < s) lo = mid + 1; else hi = mid; }
  int start = lo;
  lo = start; hi = N;
  while (lo < hi) { int mid = (lo + hi) >> 1; if (seg[mid] < s + 1) lo = mid + 1; else hi = mid; }
  int end = lo;
  if (start >= end) return;  // empty segment: out stays zero

  // denominator: sum of exp(h) over the segment's nodes
  float lsum[P_DIM];
#pragma unroll
  for (int p = 0; p < P_DIM; p++) lsum[p] = 0.f;
  for (int i = start + tid; i < end; i += 256) {
    float h[P_DIM];
    compute_h(h, pos, i, W1, b1, W2, b2);
#pragma unroll
    for (int p = 0; p < P_DIM; p++) lsum[p] += __expf(h[p]);
  }
#pragma unroll
  for (int off = 32; off >= 1; off >>= 1)
#pragma unroll
    for (int p = 0; p < P_DIM; p++)
      lsum[p] += __shfl_down(lsum[p], off, 64);

  __shared__ float wred[P_DIM][4];
  __shared__ float invd[P_DIM];
  int wid = tid >> 6, lane = tid & 63;
  if (lane == 0) {
#pragma unroll
    for (int p = 0; p < P_DIM; p++) wred[p][wid] = lsum[p];
  }
  __syncthreads();
  if (tid < P_DIM) {
    float ss = wred[tid][0] + wred[tid][1] + wred[tid][2] + wred[tid][3];
    invd[tid] = 1.f / (ss + EPS_DENOM);
  }
  __syncthreads();

  // combine tagged partials + boundary atomic contributions, scale, store
  int b0 = start / CHUNK;
  int b1i = (end - 1) / CHUNK;
  int p = (tid >> 2) & 7;  // out layout: [t][p][f], tid*8 = t*256 + p*32 + fb*8
  float s0 = invd[p];

  float* o = out + (size_t)s * OUT_PER_SEG + tid * 8;
  float4 A = reinterpret_cast<float4*>(o)[0];
  float4 B = reinterpret_cast<float4*>(o)[1];
  for (int b = b0; b <= b1i; b++) {
    if (segtag[b] == s) {
      const float4* pp = reinterpret_cast<const float4*>(
          part + (size_t)b * OUT_PER_SEG + tid * 8);
      float4 a2 = pp[0], b2v = pp[1];
      A.x += a2.x;  A.y += a2.y;  A.z += a2.z;  A.w += a2.w;
      B.x += b2v.x; B.y += b2v.y; B.z += b2v.z; B.w += b2v.w;
    }
  }
  A.x *= s0; A.y *= s0; A.z *= s0; A.w *= s0;
  B.x *= s0; B.y *= s0; B.z *= s0; B.w *= s0;
  reinterpret_cast<float4*>(o)[0] = A;
  reinterpret_cast<float4*>(o)[1] = B;
}

extern "C" void kernel_launch(void* const* d_in, const int* in_sizes, int n_in,
                              void* d_out, int out_size, void* d_ws, size_t ws_size,
                              hipStream_t stream) {
  const float* pos = (const float*)d_in[0];
  const float* x   = (const float*)d_in[1];
  const int*   seg = (const int*)d_in[2];
  const float* W1  = (const float*)d_in[3];
  const float* b1  = (const float*)d_in[4];
  const float* W2  = (const float*)d_in[5];
  const float* b2  = (const float*)d_in[6];
  float* out = (float*)d_out;
  int N = in_sizes[2];
  int nblk = (N + CHUNK - 1) / CHUNK;

  // workspace layout: segtag [nblk i32] | partials [nblk*2048 f32]
  char* ws = (char*)d_ws;
  size_t part_off = ((size_t)nblk * 4 + 255) & ~(size_t)255;
  int* segtag = (int*)ws;
  float* part = (float*)(ws + part_off);

  int zblk = (out_size / 8 + 255) / 256;
  zero_kernel<<<zblk, 256, 0, stream>>>(out, out_size);

  accum_kernel<<<nblk, K2_THREADS, 0, stream>>>(
      x, pos, seg, W1, b1, W2, b2, out, part, segtag, N);

  reduce_kernel<<<NSEG, 256, 0, stream>>>(
      seg, segtag, part, pos, W1, b1, W2, b2, out, N);
}